// Round 1
// baseline (701.762 us; speedup 1.0000x reference)
//
#include <hip/hip_runtime.h>

#define THREADS 256
#define EPT     2                      // edges per thread
#define F_HID   10
#define F_OUT   19
#define WAVEW   64
#define EPW     (WAVEW * EPT)          // 128 edges per wave
#define SLAB    (EPW * F_OUT)          // 2432 floats = 9728 B per-wave slab
#define NW      (THREADS / WAVEW)      // 4 waves per block

typedef float f32x2 __attribute__((ext_vector_type(2)));
typedef float f32x4 __attribute__((ext_vector_type(4)));
typedef int   i32x2 __attribute__((ext_vector_type(2)));

// Scalar fallback for tail blocks only (E=8M is divisible by 512, so the
// bench never takes this path; kept for generality).
__device__ __forceinline__ void mlp1(float x0, float x1, float x2, float x3,
                                     const float* __restrict__ W1,
                                     const float* __restrict__ b1,
                                     const float* __restrict__ W2,
                                     const float* __restrict__ b2,
                                     float* __restrict__ o)
{
    #pragma unroll
    for (int k = 0; k < F_OUT; ++k) o[k] = b2[k];
    #pragma unroll
    for (int j = 0; j < F_HID; ++j) {
        float a = b1[j];
        a = fmaf(x0, W1[0 * F_HID + j], a);
        a = fmaf(x1, W1[1 * F_HID + j], a);
        a = fmaf(x2, W1[2 * F_HID + j], a);
        a = fmaf(x3, W1[3 * F_HID + j], a);
        a = fmaxf(a, 0.0f);
        #pragma unroll
        for (int k = 0; k < F_OUT; ++k)
            o[k] = fmaf(a, W2[j * F_OUT + k], o[k]);
    }
}

__global__ __launch_bounds__(THREADS) void edge_mlp_kernel(
    const float* __restrict__ src,
    const float* __restrict__ dst,
    const float* __restrict__ ea,
    const float* __restrict__ u,      // [B,1], 16 KB, L1-resident
    const int*   __restrict__ batch,  // [E] int32
    const float* __restrict__ W1,     // [4,10] row-major
    const float* __restrict__ b1,     // [10]
    const float* __restrict__ W2,     // [10,19] row-major
    const float* __restrict__ b2,     // [19]
    float* __restrict__ out,          // [E,19]
    int n_edges)
{
    // Per-wave slabs: each wave stages its 128 edges' outputs in a slab laid
    // out exactly like the global region it maps to. Wave-synchronous (DS
    // pipe is in-order per wave) -> no __syncthreads, no block-wide
    // vmcnt/lgkmcnt drain. 38912 B/block -> 4 blocks/CU.
    __shared__ float lds[NW * SLAB];

    const int tid  = threadIdx.x;
    const int lane = tid & (WAVEW - 1);
    const int wv   = tid >> 6;
    const int bs   = blockIdx.x * (THREADS * EPT);

    if (bs + THREADS * EPT <= n_edges) {
        // ---- fast path: full block ----
        const int e0 = bs + wv * EPW + lane * EPT;   // even -> 8B aligned

        // Vectorized input loads: 8 B/lane, fully coalesced (512 B/wave-instr).
        const f32x2 xs = *(const f32x2*)(src + e0);
        const f32x2 xd = *(const f32x2*)(dst + e0);
        const f32x2 xa = *(const f32x2*)(ea  + e0);
        const i32x2 bi = *(const i32x2*)(batch + e0);
        f32x2 xu; xu.x = u[bi.x]; xu.y = u[bi.y];

        // o[0..18] = edge e0, o[19..37] = edge e0+1 (matches global layout).
        float o[EPT * F_OUT];
        #pragma unroll
        for (int k = 0; k < F_OUT; ++k) { o[k] = b2[k]; o[F_OUT + k] = b2[k]; }

        // Dual-edge MLP: weight scalars (SGPR broadcasts) amortized over 2 edges.
        #pragma unroll
        for (int j = 0; j < F_HID; ++j) {
            const float w0 = W1[0 * F_HID + j];
            const float w1 = W1[1 * F_HID + j];
            const float w2 = W1[2 * F_HID + j];
            const float w3 = W1[3 * F_HID + j];
            const float bb = b1[j];

            float a0 = fmaf(xu.x, w3, bb);
            a0 = fmaf(xa.x, w2, a0);
            a0 = fmaf(xd.x, w1, a0);
            a0 = fmaf(xs.x, w0, a0);
            a0 = fmaxf(a0, 0.0f);

            float a1 = fmaf(xu.y, w3, bb);
            a1 = fmaf(xa.y, w2, a1);
            a1 = fmaf(xd.y, w1, a1);
            a1 = fmaf(xs.y, w0, a1);
            a1 = fmaxf(a1, 0.0f);

            #pragma unroll
            for (int k = 0; k < F_OUT; ++k) {
                const float w = W2[j * F_OUT + k];
                o[k]         = fmaf(a0, w, o[k]);
                o[F_OUT + k] = fmaf(a1, w, o[F_OUT + k]);
            }
        }

        // Stage: thread owns 38 CONSECUTIVE floats (152 B, 8B-aligned) ->
        // 19 ds_write_b64 (vs 38 ds_write_b32). Lane stride 152 B: start
        // banks 6*lane mod 32 -> ~4-way max, far from LDS-bound.
        float* slab = lds + wv * SLAB;
        {
            f32x2* my = (f32x2*)(slab + lane * (EPT * F_OUT));
            #pragma unroll
            for (int p = 0; p < (EPT * F_OUT) / 2; ++p) {
                f32x2 t;
                t.x = o[2 * p];
                t.y = o[2 * p + 1];
                my[p] = t;
            }
        }
        __builtin_amdgcn_wave_barrier();  // compile-time fence; DS is in-order per wave

        // Coalesced, non-temporal copy: slab (9728 B) -> out. 608 f32x4 per
        // wave; 16B-aligned on both sides (9728 % 16 == 0, 512*76 % 16 == 0).
        {
            const f32x4* sv = (const f32x4*)slab;
            f32x4* ov = (f32x4*)(out + (size_t)(bs + wv * EPW) * F_OUT);
            for (int idx = lane; idx < SLAB / 4; idx += WAVEW)
                __builtin_nontemporal_store(sv[idx], ov + idx);
        }
    } else {
        // ---- tail block: scalar per-edge path (not hit for E=8M) ----
        const int e0 = bs + wv * EPW + lane * EPT;
        #pragma unroll
        for (int r = 0; r < EPT; ++r) {
            const int e = e0 + r;
            if (e < n_edges) {
                float o[F_OUT];
                mlp1(src[e], dst[e], ea[e], u[batch[e]], W1, b1, W2, b2, o);
                #pragma unroll
                for (int k = 0; k < F_OUT; ++k)
                    out[(size_t)e * F_OUT + k] = o[k];
            }
        }
    }
}

extern "C" void kernel_launch(void* const* d_in, const int* in_sizes, int n_in,
                              void* d_out, int out_size, void* d_ws, size_t ws_size,
                              hipStream_t stream) {
    const float* src   = (const float*)d_in[0];
    const float* dst   = (const float*)d_in[1];
    const float* ea    = (const float*)d_in[2];
    const float* u     = (const float*)d_in[3];
    const int*   batch = (const int*)  d_in[4];
    const float* W1    = (const float*)d_in[5];
    const float* b1    = (const float*)d_in[6];
    const float* W2    = (const float*)d_in[7];
    const float* b2    = (const float*)d_in[8];
    float* out = (float*)d_out;

    const int n = in_sizes[0];  // E (src is [E,1])
    const int edges_per_block = THREADS * EPT;                 // 512
    const int blocks = (n + edges_per_block - 1) / edges_per_block;  // 15625 for E=8M
    edge_mlp_kernel<<<blocks, THREADS, 0, stream>>>(
        src, dst, ea, u, batch, W1, b1, W2, b2, out, n);
}